// Round 1
// baseline (4368.832 us; speedup 1.0000x reference)
//
#include <hip/hip_runtime.h>

// Weighted furthest point sampling + gathers for KeypointDetector.
// B=16, N=16384, C=128, S=1024, SEM=20.
//
// Output layout (float*, concatenated in reference return order):
//   [0, 49152)                  sampled_xyz      [B,S,3]
//   [49152, 49152+2097152)      sample_seg_feat  [B,C,S]
//   [2146304, 2162688)          sample_seg_label [B,S] (stored as float)

#define FPS_B   16
#define FPS_N   16384
#define FPS_C   128
#define FPS_S   1024
#define FPS_SEM 20
#define FPS_T   1024
#define FPS_PPT 16   // points per thread = N / T

__global__ __launch_bounds__(FPS_T) void wfps_kernel(
    const float* __restrict__ xyz,    // [B,N,3]
    const int*   __restrict__ label,  // [B,N]
    int*         __restrict__ idx_out) // [B,S]
{
  const int b = blockIdx.x;
  const int t = threadIdx.x;

  __shared__ int counts[FPS_SEM];
  __shared__ unsigned long long wavemax[16];
  __shared__ float lp_s[3];

  if (t < FPS_SEM) counts[t] = 0;
  __syncthreads();

  // ---- class-frequency weights ----
  const int* lab = label + (long long)b * FPS_N;
  int mylab[FPS_PPT];
#pragma unroll
  for (int k = 0; k < FPS_PPT; ++k) {
    mylab[k] = lab[t + k * FPS_T];
    atomicAdd(&counts[mylab[k]], 1);
  }
  __syncthreads();

  // ---- load my 16 points into registers ----
  const float* xb = xyz + (long long)b * FPS_N * 3;
  float px[FPS_PPT], py[FPS_PPT], pz[FPS_PPT], w[FPS_PPT], mind[FPS_PPT];
  unsigned int nlo[FPS_PPT];
#pragma unroll
  for (int k = 0; k < FPS_PPT; ++k) {
    int n = t + k * FPS_T;
    px[k] = xb[n * 3 + 0];
    py[k] = xb[n * 3 + 1];
    pz[k] = xb[n * 3 + 2];
    w[k] = (float)counts[mylab[k]];
    mind[k] = 1e10f;
    nlo[k] = ~(unsigned)n;   // packed low word: larger == smaller index
  }

  if (t == 0) {
    idx_out[(long long)b * FPS_S] = 0;
    lp_s[0] = px[0]; lp_s[1] = py[0]; lp_s[2] = pz[0];
  }
  __syncthreads();
  float lx = lp_s[0], ly = lp_s[1], lz = lp_s[2];

  // ---- serial FPS loop ----
  for (int s = 1; s < FPS_S; ++s) {
    unsigned long long best = 0ull;
#pragma unroll
    for (int k = 0; k < FPS_PPT; ++k) {
      // exact IEEE ops, no contraction, numpy summation order
      float dx = __fsub_rn(px[k], lx);
      float dy = __fsub_rn(py[k], ly);
      float dz = __fsub_rn(pz[k], lz);
      float d  = __fadd_rn(__fadd_rn(__fmul_rn(dx, dx), __fmul_rn(dy, dy)),
                           __fmul_rn(dz, dz));
      float m = fminf(mind[k], d);
      mind[k] = m;
      float sc = __fmul_rn(m, w[k]);
      unsigned long long p =
          ((unsigned long long)__float_as_uint(sc) << 32) | (unsigned long long)nlo[k];
      best = (p > best) ? p : best;
    }

    // wave (64-lane) max reduce
#pragma unroll
    for (int off = 32; off > 0; off >>= 1) {
      unsigned long long o = __shfl_xor(best, off, 64);
      best = (o > best) ? o : best;
    }
    if ((t & 63) == 0) wavemax[t >> 6] = best;
    __syncthreads();

    // every wave re-reduces the 16 wave partials (broadcast reads + 4 shfl steps)
    best = wavemax[t & 15];
#pragma unroll
    for (int off = 8; off > 0; off >>= 1) {
      unsigned long long o = __shfl_xor(best, off, 64);
      best = (o > best) ? o : best;
    }
    int cur = (int)(~(unsigned)best);  // recover winning index

    // owner thread broadcasts selected point coords from its registers
    int ot = cur & (FPS_T - 1);
    if (t == ot) {
      int ok = cur >> 10;
      float sx = px[0], sy = py[0], sz = pz[0];
#pragma unroll
      for (int k = 1; k < FPS_PPT; ++k) {  // static indices only (no scratch)
        if (ok == k) { sx = px[k]; sy = py[k]; sz = pz[k]; }
      }
      lp_s[0] = sx; lp_s[1] = sy; lp_s[2] = sz;
      idx_out[(long long)b * FPS_S + s] = cur;
    }
    __syncthreads();
    lx = lp_s[0]; ly = lp_s[1]; lz = lp_s[2];
  }
}

__global__ void gather_kernel(
    const float* __restrict__ xyz,    // [B,N,3]
    const float* __restrict__ feat,   // [B,C,N]
    const int*   __restrict__ label,  // [B,N]
    const int*   __restrict__ idx,    // [B,S]
    float*       __restrict__ out)
{
  const long long FEAT = (long long)FPS_B * FPS_C * FPS_S;  // 2097152
  const int XYZN = FPS_B * FPS_S * 3;                       // 49152
  const int LABN = FPS_B * FPS_S;                           // 16384
  long long i = (long long)blockIdx.x * blockDim.x + threadIdx.x;

  if (i < FEAT) {
    // sample_seg_feature [B,C,S]
    int s = (int)(i & (FPS_S - 1));
    int c = (int)((i >> 10) & (FPS_C - 1));
    int b = (int)(i >> 17);
    int n = idx[b * FPS_S + s];
    out[XYZN + i] = feat[((long long)(b * FPS_C + c)) * FPS_N + n];
  } else if (i < FEAT + XYZN) {
    // sampled_xyz [B,S,3]
    int j = (int)(i - FEAT);
    int d = j % 3;
    int sb = j / 3;
    int s = sb & (FPS_S - 1);
    int b = sb >> 10;
    int n = idx[b * FPS_S + s];
    out[j] = xyz[((long long)b * FPS_N + n) * 3 + d];
  } else if (i < FEAT + XYZN + LABN) {
    // sample_seg_label [B,S] as float
    int j = (int)(i - FEAT - XYZN);
    int s = j & (FPS_S - 1);
    int b = j >> 10;
    int n = idx[b * FPS_S + s];
    out[FEAT + XYZN + j] = (float)label[b * FPS_N + n];
  }
}

extern "C" void kernel_launch(void* const* d_in, const int* in_sizes, int n_in,
                              void* d_out, int out_size, void* d_ws, size_t ws_size,
                              hipStream_t stream) {
  const float* xyz   = (const float*)d_in[0];
  const float* feat  = (const float*)d_in[1];
  const int*   label = (const int*)d_in[2];
  float* out = (float*)d_out;
  int*   idx = (int*)d_ws;  // B*S ints = 64 KiB scratch

  wfps_kernel<<<FPS_B, FPS_T, 0, stream>>>(xyz, label, idx);

  const long long total = (long long)FPS_B * FPS_C * FPS_S
                        + (long long)FPS_B * FPS_S * 3
                        + (long long)FPS_B * FPS_S;  // 2162688
  gather_kernel<<<(int)((total + 255) / 256), 256, 0, stream>>>(
      xyz, feat, label, idx, out);
}

// Round 2
// 1919.554 us; speedup vs baseline: 2.2760x; 2.2760x over previous
//
#include <hip/hip_runtime.h>

// Weighted furthest point sampling + gathers for KeypointDetector.
// B=16, N=16384, C=128, S=1024, SEM=20.
//
// Output layout (float*, concatenated in reference return order):
//   [0, 49152)                  sampled_xyz      [B,S,3]
//   [49152, 49152+2097152)      sample_seg_feat  [B,C,S]
//   [2146304, 2162688)          sample_seg_label [B,S] (stored as float)

#define FPS_B   16
#define FPS_N   16384
#define FPS_C   128
#define FPS_S   1024
#define FPS_SEM 20
#define FPS_T   1024
#define FPS_PPT 16   // points per thread = N / T

__global__ __launch_bounds__(FPS_T, 4) void wfps_kernel(
    const float* __restrict__ xyz,    // [B,N,3]
    const int*   __restrict__ label,  // [B,N]
    int*         __restrict__ idx_out) // [B,S]
{
  const int b = blockIdx.x;
  const int t = threadIdx.x;

  __shared__ int counts[FPS_SEM];
  __shared__ unsigned long long wmax[2][16];

  if (t < FPS_SEM) counts[t] = 0;
  __syncthreads();

  // ---- class-frequency weights ----
  const int* lab = label + (long long)b * FPS_N;
  int mylab[FPS_PPT];
#pragma unroll
  for (int k = 0; k < FPS_PPT; ++k) {
    mylab[k] = lab[t + k * FPS_T];
    atomicAdd(&counts[mylab[k]], 1);
  }
  __syncthreads();

  // ---- load my 16 points into registers (kept resident: ~100 VGPRs) ----
  const float* xb = xyz + (long long)b * FPS_N * 3;
  float px[FPS_PPT], py[FPS_PPT], pz[FPS_PPT], w[FPS_PPT], mind[FPS_PPT];
#pragma unroll
  for (int k = 0; k < FPS_PPT; ++k) {
    int n = t + k * FPS_T;
    px[k] = xb[n * 3 + 0];
    py[k] = xb[n * 3 + 1];
    pz[k] = xb[n * 3 + 2];
    w[k] = (float)counts[mylab[k]];
    mind[k] = 1e10f;
  }

  if (t == 0) idx_out[(long long)b * FPS_S] = 0;
  // initial selected point: index 0 — uniform global load, L2-cached
  float lx = xb[0], ly = xb[1], lz = xb[2];

  // ---- serial FPS loop: ONE barrier per step ----
  for (int s = 1; s < FPS_S; ++s) {
    // local best over my 16 points: strict '>' keeps smallest k (== smallest n)
    float bs = -1.0f;
    int bk = 0;
#pragma unroll
    for (int k = 0; k < FPS_PPT; ++k) {
      // exact IEEE ops, no contraction, numpy summation order
      float dx = __fsub_rn(px[k], lx);
      float dy = __fsub_rn(py[k], ly);
      float dz = __fsub_rn(pz[k], lz);
      float d  = __fadd_rn(__fadd_rn(__fmul_rn(dx, dx), __fmul_rn(dy, dy)),
                           __fmul_rn(dz, dz));
      float m = fminf(mind[k], d);
      mind[k] = m;
      float sc = __fmul_rn(m, w[k]);
      bool g = sc > bs;
      bs = g ? sc : bs;
      bk = g ? k : bk;   // k is an inline constant -> no index array needed
    }
    // pack (score_bits, ~n): u64 max == (max score, then smallest index)
    unsigned n = (unsigned)t + ((unsigned)bk << 10);
    unsigned long long best =
        ((unsigned long long)__float_as_uint(bs) << 32) |
        (unsigned long long)(~n);

    // wave (64-lane) max reduce
#pragma unroll
    for (int off = 32; off > 0; off >>= 1) {
      unsigned long long o = __shfl_xor(best, off, 64);
      best = (o > best) ? o : best;
    }
    unsigned long long* wm = wmax[s & 1];  // double-buffer: no 2nd barrier
    if ((t & 63) == 0) wm[t >> 6] = best;
    __syncthreads();

    // every wave re-reduces the 16 wave partials
    best = wm[t & 15];
#pragma unroll
    for (int off = 8; off > 0; off >>= 1) {
      unsigned long long o = __shfl_xor(best, off, 64);
      best = (o > best) ? o : best;
    }
    int cur = (int)(~(unsigned)best);

    if (t == 0) idx_out[(long long)b * FPS_S + s] = cur;

    // all threads read the selected point directly (uniform, L2-cached):
    // removes owner-broadcast + second barrier from the critical path
    const float* q = xb + 3 * cur;
    lx = q[0]; ly = q[1]; lz = q[2];
  }
}

__global__ void gather_kernel(
    const float* __restrict__ xyz,    // [B,N,3]
    const float* __restrict__ feat,   // [B,C,N]
    const int*   __restrict__ label,  // [B,N]
    const int*   __restrict__ idx,    // [B,S]
    float*       __restrict__ out)
{
  const long long FEAT = (long long)FPS_B * FPS_C * FPS_S;  // 2097152
  const int XYZN = FPS_B * FPS_S * 3;                       // 49152
  const int LABN = FPS_B * FPS_S;                           // 16384
  long long i = (long long)blockIdx.x * blockDim.x + threadIdx.x;

  if (i < FEAT) {
    // sample_seg_feature [B,C,S]
    int s = (int)(i & (FPS_S - 1));
    int c = (int)((i >> 10) & (FPS_C - 1));
    int b = (int)(i >> 17);
    int n = idx[b * FPS_S + s];
    out[XYZN + i] = feat[((long long)(b * FPS_C + c)) * FPS_N + n];
  } else if (i < FEAT + XYZN) {
    // sampled_xyz [B,S,3]
    int j = (int)(i - FEAT);
    int d = j % 3;
    int sb = j / 3;
    int s = sb & (FPS_S - 1);
    int b = sb >> 10;
    int n = idx[b * FPS_S + s];
    out[j] = xyz[((long long)b * FPS_N + n) * 3 + d];
  } else if (i < FEAT + XYZN + LABN) {
    // sample_seg_label [B,S] as float
    int j = (int)(i - FEAT - XYZN);
    int s = j & (FPS_S - 1);
    int b = j >> 10;
    int n = idx[b * FPS_S + s];
    out[FEAT + XYZN + j] = (float)label[b * FPS_N + n];
  }
}

extern "C" void kernel_launch(void* const* d_in, const int* in_sizes, int n_in,
                              void* d_out, int out_size, void* d_ws, size_t ws_size,
                              hipStream_t stream) {
  const float* xyz   = (const float*)d_in[0];
  const float* feat  = (const float*)d_in[1];
  const int*   label = (const int*)d_in[2];
  float* out = (float*)d_out;
  int*   idx = (int*)d_ws;  // B*S ints = 64 KiB scratch

  wfps_kernel<<<FPS_B, FPS_T, 0, stream>>>(xyz, label, idx);

  const long long total = (long long)FPS_B * FPS_C * FPS_S
                        + (long long)FPS_B * FPS_S * 3
                        + (long long)FPS_B * FPS_S;  // 2162688
  gather_kernel<<<(int)((total + 255) / 256), 256, 0, stream>>>(
      xyz, feat, label, idx, out);
}

// Round 4
// 1917.865 us; speedup vs baseline: 2.2780x; 1.0009x over previous
//
#include <hip/hip_runtime.h>

// Weighted furthest point sampling + gathers for KeypointDetector.
// B=16, N=16384, C=128, S=1024, SEM=20.
//
// Output layout (float*, concatenated in reference return order):
//   [0, 49152)                  sampled_xyz      [B,S,3]
//   [49152, 49152+2097152)      sample_seg_feat  [B,C,S]
//   [2146304, 2162688)          sample_seg_label [B,S] (stored as float)

#define FPS_B   16
#define FPS_N   16384
#define FPS_C   128
#define FPS_S   1024
#define FPS_SEM 20
#define FPS_T   512
#define FPS_PPT 32   // points per thread = N / T

__global__ __launch_bounds__(FPS_T, 2) void wfps_kernel(
    const float* __restrict__ xyz,    // [B,N,3]
    const int*   __restrict__ label,  // [B,N]
    int*         __restrict__ idx_out) // [B,S]
{
  const int b = blockIdx.x;
  const int t = threadIdx.x;

  __shared__ int counts[FPS_SEM];
  __shared__ unsigned long long wmax[2][8];

  if (t < FPS_SEM) counts[t] = 0;
  __syncthreads();

  // ---- class-frequency weights ----
  const int* lab = label + (long long)b * FPS_N;
  int mylab[FPS_PPT];
#pragma unroll
  for (int k = 0; k < FPS_PPT; ++k) {
    mylab[k] = lab[t + k * FPS_T];
    atomicAdd(&counts[mylab[k]], 1);
  }
  __syncthreads();

  // ---- load my 32 points into registers (~160 VGPRs of state; fits in the
  // 256-VGPR budget granted by __launch_bounds__(512,2) => no AGPR shuttling)
  const float* xb = xyz + (long long)b * FPS_N * 3;
  float px[FPS_PPT], py[FPS_PPT], pz[FPS_PPT], w[FPS_PPT], mind[FPS_PPT];
#pragma unroll
  for (int k = 0; k < FPS_PPT; ++k) {
    int n = t + k * FPS_T;
    px[k] = xb[n * 3 + 0];
    py[k] = xb[n * 3 + 1];
    pz[k] = xb[n * 3 + 2];
    w[k] = (float)counts[mylab[k]];
    mind[k] = 1e10f;
  }

  if (t == 0) idx_out[(long long)b * FPS_S] = 0;
  float lx = xb[0], ly = xb[1], lz = xb[2];

  // ---- serial FPS loop: one barrier per step ----
  for (int s = 1; s < FPS_S; ++s) {
    // local best over my 32 points: strict '>' keeps smallest k (== smallest n)
    float bs = -1.0f;
    int bk = 0;
#pragma unroll
    for (int k = 0; k < FPS_PPT; ++k) {
      // exact IEEE ops via _rn intrinsics: un-fusable, numpy summation order
      float dx = __fsub_rn(px[k], lx);
      float dy = __fsub_rn(py[k], ly);
      float dz = __fsub_rn(pz[k], lz);
      float d  = __fadd_rn(__fadd_rn(__fmul_rn(dx, dx), __fmul_rn(dy, dy)),
                           __fmul_rn(dz, dz));
      float m = fminf(mind[k], d);
      mind[k] = m;
      float sc = __fmul_rn(m, w[k]);
      bool g = sc > bs;
      bs = g ? sc : bs;
      bk = g ? k : bk;   // k is an inline constant -> no index array
    }
    // pack (score_bits, ~n): u64 max == (max score, then smallest index)
    unsigned n = (unsigned)t + ((unsigned)bk << 9);   // n = t + bk*512
    unsigned long long best =
        ((unsigned long long)__float_as_uint(bs) << 32) |
        (unsigned long long)(~n);

    // wave (64-lane) max reduce
#pragma unroll
    for (int off = 32; off > 0; off >>= 1) {
      unsigned long long o = __shfl_xor(best, off, 64);
      best = (o > best) ? o : best;
    }
    unsigned long long* wm = wmax[s & 1];  // double-buffer: one barrier/step
    if ((t & 63) == 0) wm[t >> 6] = best;
    __syncthreads();

    // every wave re-reduces the 8 wave partials
    best = wm[t & 7];
#pragma unroll
    for (int off = 4; off > 0; off >>= 1) {
      unsigned long long o = __shfl_xor(best, off, 64);
      best = (o > best) ? o : best;
    }
    int cur = (int)(~(unsigned)best);

    if (t == 0) idx_out[(long long)b * FPS_S + s] = cur;

    // selected point coords: uniform L2/L1-cached load (off the barrier path)
    const float* q = xb + 3 * cur;
    lx = q[0]; ly = q[1]; lz = q[2];
  }
}

__global__ void gather_kernel(
    const float* __restrict__ xyz,    // [B,N,3]
    const float* __restrict__ feat,   // [B,C,N]
    const int*   __restrict__ label,  // [B,N]
    const int*   __restrict__ idx,    // [B,S]
    float*       __restrict__ out)
{
  const long long FEAT = (long long)FPS_B * FPS_C * FPS_S;  // 2097152
  const int XYZN = FPS_B * FPS_S * 3;                       // 49152
  const int LABN = FPS_B * FPS_S;                           // 16384
  long long i = (long long)blockIdx.x * blockDim.x + threadIdx.x;

  if (i < FEAT) {
    // sample_seg_feature [B,C,S]
    int s = (int)(i & (FPS_S - 1));
    int c = (int)((i >> 10) & (FPS_C - 1));
    int b = (int)(i >> 17);
    int n = idx[b * FPS_S + s];
    out[XYZN + i] = feat[((long long)(b * FPS_C + c)) * FPS_N + n];
  } else if (i < FEAT + XYZN) {
    // sampled_xyz [B,S,3]
    int j = (int)(i - FEAT);
    int d = j % 3;
    int sb = j / 3;
    int s = sb & (FPS_S - 1);
    int b = sb >> 10;
    int n = idx[b * FPS_S + s];
    out[j] = xyz[((long long)b * FPS_N + n) * 3 + d];
  } else if (i < FEAT + XYZN + LABN) {
    // sample_seg_label [B,S] as float
    int j = (int)(i - FEAT - XYZN);
    int s = j & (FPS_S - 1);
    int b = j >> 10;
    int n = idx[b * FPS_S + s];
    out[FEAT + XYZN + j] = (float)label[b * FPS_N + n];
  }
}

extern "C" void kernel_launch(void* const* d_in, const int* in_sizes, int n_in,
                              void* d_out, int out_size, void* d_ws, size_t ws_size,
                              hipStream_t stream) {
  const float* xyz   = (const float*)d_in[0];
  const float* feat  = (const float*)d_in[1];
  const int*   label = (const int*)d_in[2];
  float* out = (float*)d_out;
  int*   idx = (int*)d_ws;  // B*S ints = 64 KiB scratch

  wfps_kernel<<<FPS_B, FPS_T, 0, stream>>>(xyz, label, idx);

  const long long total = (long long)FPS_B * FPS_C * FPS_S
                        + (long long)FPS_B * FPS_S * 3
                        + (long long)FPS_B * FPS_S;  // 2162688
  gather_kernel<<<(int)((total + 255) / 256), 256, 0, stream>>>(
      xyz, feat, label, idx, out);
}

// Round 6
// 1913.331 us; speedup vs baseline: 2.2834x; 1.0024x over previous
//
#include <hip/hip_runtime.h>

// Weighted furthest point sampling + gathers for KeypointDetector.
// B=16, N=16384, C=128, S=1024, SEM=20.
//
// Output layout (float*, concatenated in reference return order):
//   [0, 49152)                  sampled_xyz      [B,S,3]
//   [49152, 49152+2097152)      sample_seg_feat  [B,C,S]
//   [2146304, 2162688)          sample_seg_label [B,S] (stored as float)

#define FPS_B   16
#define FPS_N   16384
#define FPS_C   128
#define FPS_S   1024
#define FPS_SEM 20
#define FPS_T   512
#define FPS_PPT 32   // points per thread = N / T

// amdgpu_waves_per_eu(2,2): pin EXACTLY 2 waves/EU (one 512-thread block/CU)
// so the register allocator gets the full 256-VGPR arch budget. R4 showed
// __launch_bounds__(512,2) alone still targeted 4 waves/EU (128 regs) and
// shuttled ~70 regs of point state through AGPRs via v_accvgpr_read/write —
// VALU-issued, ~2x the mandatory inner-loop issue. State is ~190 regs < 256.
__global__ __launch_bounds__(FPS_T)
__attribute__((amdgpu_waves_per_eu(2, 2)))
void wfps_kernel(
    const float* __restrict__ xyz,    // [B,N,3]
    const int*   __restrict__ label,  // [B,N]
    int*         __restrict__ idx_out) // [B,S]
{
  const int b = blockIdx.x;
  const int t = threadIdx.x;

  __shared__ int counts[FPS_SEM];
  __shared__ unsigned long long wmax[2][8];

  if (t < FPS_SEM) counts[t] = 0;
  __syncthreads();

  // ---- class-frequency weights ----
  const int* lab = label + (long long)b * FPS_N;
  int mylab[FPS_PPT];
#pragma unroll
  for (int k = 0; k < FPS_PPT; ++k) {
    mylab[k] = lab[t + k * FPS_T];
    atomicAdd(&counts[mylab[k]], 1);
  }
  __syncthreads();

  // ---- load my 32 points into registers (arch-VGPR resident, no AGPR) ----
  const float* xb = xyz + (long long)b * FPS_N * 3;
  float px[FPS_PPT], py[FPS_PPT], pz[FPS_PPT], w[FPS_PPT], mind[FPS_PPT];
#pragma unroll
  for (int k = 0; k < FPS_PPT; ++k) {
    int n = t + k * FPS_T;
    px[k] = xb[n * 3 + 0];
    py[k] = xb[n * 3 + 1];
    pz[k] = xb[n * 3 + 2];
    w[k] = (float)counts[mylab[k]];
    mind[k] = 1e10f;
  }

  if (t == 0) idx_out[(long long)b * FPS_S] = 0;
  float lx = xb[0], ly = xb[1], lz = xb[2];

  // ---- serial FPS loop: one barrier per step ----
  for (int s = 1; s < FPS_S; ++s) {
    // local best over my 32 points: strict '>' keeps smallest k (== smallest n)
    float bs = -1.0f;
    int bk = 0;
#pragma unroll
    for (int k = 0; k < FPS_PPT; ++k) {
      // exact IEEE ops via _rn intrinsics: un-fusable, numpy summation order
      float dx = __fsub_rn(px[k], lx);
      float dy = __fsub_rn(py[k], ly);
      float dz = __fsub_rn(pz[k], lz);
      float d  = __fadd_rn(__fadd_rn(__fmul_rn(dx, dx), __fmul_rn(dy, dy)),
                           __fmul_rn(dz, dz));
      float m = fminf(mind[k], d);
      mind[k] = m;
      float sc = __fmul_rn(m, w[k]);
      bool g = sc > bs;
      bs = g ? sc : bs;
      bk = g ? k : bk;   // k is an inline constant -> no index array
    }
    // pack (score_bits, ~n): u64 max == (max score, then smallest index)
    unsigned n = (unsigned)t + ((unsigned)bk << 9);   // n = t + bk*512
    unsigned long long best =
        ((unsigned long long)__float_as_uint(bs) << 32) |
        (unsigned long long)(~n);

    // wave (64-lane) max reduce
#pragma unroll
    for (int off = 32; off > 0; off >>= 1) {
      unsigned long long o = __shfl_xor(best, off, 64);
      best = (o > best) ? o : best;
    }
    unsigned long long* wm = wmax[s & 1];  // double-buffer: one barrier/step
    if ((t & 63) == 0) wm[t >> 6] = best;
    __syncthreads();

    // every wave re-reduces the 8 wave partials
    best = wm[t & 7];
#pragma unroll
    for (int off = 4; off > 0; off >>= 1) {
      unsigned long long o = __shfl_xor(best, off, 64);
      best = (o > best) ? o : best;
    }
    int cur = (int)(~(unsigned)best);

    if (t == 0) idx_out[(long long)b * FPS_S + s] = cur;

    // selected point coords: uniform L1/L2-cached load (off the barrier path)
    const float* q = xb + 3 * cur;
    lx = q[0]; ly = q[1]; lz = q[2];
  }
}

__global__ void gather_kernel(
    const float* __restrict__ xyz,    // [B,N,3]
    const float* __restrict__ feat,   // [B,C,N]
    const int*   __restrict__ label,  // [B,N]
    const int*   __restrict__ idx,    // [B,S]
    float*       __restrict__ out)
{
  const long long FEAT = (long long)FPS_B * FPS_C * FPS_S;  // 2097152
  const int XYZN = FPS_B * FPS_S * 3;                       // 49152
  const int LABN = FPS_B * FPS_S;                           // 16384
  long long i = (long long)blockIdx.x * blockDim.x + threadIdx.x;

  if (i < FEAT) {
    // sample_seg_feature [B,C,S]
    int s = (int)(i & (FPS_S - 1));
    int c = (int)((i >> 10) & (FPS_C - 1));
    int b = (int)(i >> 17);
    int n = idx[b * FPS_S + s];
    out[XYZN + i] = feat[((long long)(b * FPS_C + c)) * FPS_N + n];
  } else if (i < FEAT + XYZN) {
    // sampled_xyz [B,S,3]
    int j = (int)(i - FEAT);
    int d = j % 3;
    int sb = j / 3;
    int s = sb & (FPS_S - 1);
    int b = sb >> 10;
    int n = idx[b * FPS_S + s];
    out[j] = xyz[((long long)b * FPS_N + n) * 3 + d];
  } else if (i < FEAT + XYZN + LABN) {
    // sample_seg_label [B,S] as float
    int j = (int)(i - FEAT - XYZN);
    int s = j & (FPS_S - 1);
    int b = j >> 10;
    int n = idx[b * FPS_S + s];
    out[FEAT + XYZN + j] = (float)label[b * FPS_N + n];
  }
}

extern "C" void kernel_launch(void* const* d_in, const int* in_sizes, int n_in,
                              void* d_out, int out_size, void* d_ws, size_t ws_size,
                              hipStream_t stream) {
  const float* xyz   = (const float*)d_in[0];
  const float* feat  = (const float*)d_in[1];
  const int*   label = (const int*)d_in[2];
  float* out = (float*)d_out;
  int*   idx = (int*)d_ws;  // B*S ints = 64 KiB scratch

  wfps_kernel<<<FPS_B, FPS_T, 0, stream>>>(xyz, label, idx);

  const long long total = (long long)FPS_B * FPS_C * FPS_S
                        + (long long)FPS_B * FPS_S * 3
                        + (long long)FPS_B * FPS_S;  // 2162688
  gather_kernel<<<(int)((total + 255) / 256), 256, 0, stream>>>(
      xyz, feat, label, idx, out);
}

// Round 7
// 1892.425 us; speedup vs baseline: 2.3086x; 1.0110x over previous
//
#include <hip/hip_runtime.h>

// Weighted furthest point sampling + gathers for KeypointDetector.
// B=16, N=16384, C=128, S=1024, SEM=20.
//
// Output layout (float*, concatenated in reference return order):
//   [0, 49152)                  sampled_xyz      [B,S,3]
//   [49152, 49152+2097152)      sample_seg_feat  [B,C,S]
//   [2146304, 2162688)          sample_seg_label [B,S] (stored as float)

#define FPS_B   16
#define FPS_N   16384
#define FPS_C   128
#define FPS_S   1024
#define FPS_SEM 20
#define FPS_T   1024
#define FPS_PPT 16   // points per thread = N / T

// Pin exactly 4 waves/EU (= one 1024-thread block per CU, 128-VGPR budget).
// State px/py/pz/w/mind = 80 VGPRs + temps ~= 110 fits without spill.
__global__ __launch_bounds__(FPS_T)
__attribute__((amdgpu_waves_per_eu(4, 4)))
void wfps_kernel(
    const float* __restrict__ xyz,    // [B,N,3]
    const int*   __restrict__ label,  // [B,N]
    int*         __restrict__ idx_out) // [B,S]
{
  const int b = blockIdx.x;
  const int t = threadIdx.x;

  __shared__ int counts[FPS_SEM];
  __shared__ unsigned long long wmax[FPS_S];  // one slot per step, zeroed once

  if (t < FPS_SEM) counts[t] = 0;
  wmax[t] = 0ull;   // T == FPS_S: each thread zeroes one slot
  __syncthreads();

  // ---- class-frequency weights ----
  const int* lab = label + (long long)b * FPS_N;
  int mylab[FPS_PPT];
#pragma unroll
  for (int k = 0; k < FPS_PPT; ++k) {
    mylab[k] = lab[t + k * FPS_T];
    atomicAdd(&counts[mylab[k]], 1);
  }
  __syncthreads();

  // ---- load my 16 points into registers and FORCE residency ----
  // R2/R4/R6 all ran at the same speed with VGPR_Count << live state: the
  // compiler was sinking these loads into the step loop (re-load from L1/L2
  // every step). The empty asm makes each value opaque — un-rematerializable,
  // so it must stay in a register for the whole kernel.
  const float* xb = xyz + (long long)b * FPS_N * 3;
  float px[FPS_PPT], py[FPS_PPT], pz[FPS_PPT], w[FPS_PPT], mind[FPS_PPT];
#pragma unroll
  for (int k = 0; k < FPS_PPT; ++k) {
    int n = t + k * FPS_T;
    px[k] = xb[n * 3 + 0];
    py[k] = xb[n * 3 + 1];
    pz[k] = xb[n * 3 + 2];
    w[k] = (float)counts[mylab[k]];
    mind[k] = 1e10f;
    asm("" : "+v"(px[k]), "+v"(py[k]), "+v"(pz[k]), "+v"(w[k]));
  }

  if (t == 0) idx_out[(long long)b * FPS_S] = 0;
  float lx = xb[0], ly = xb[1], lz = xb[2];

  // ---- serial FPS loop: one barrier per step ----
  for (int s = 1; s < FPS_S; ++s) {
    // local best over my 16 points: strict '>' keeps smallest k (== smallest n)
    float bs = -1.0f;
    int bk = 0;
#pragma unroll
    for (int k = 0; k < FPS_PPT; ++k) {
      // exact IEEE ops via _rn intrinsics: un-fusable, numpy summation order
      float dx = __fsub_rn(px[k], lx);
      float dy = __fsub_rn(py[k], ly);
      float dz = __fsub_rn(pz[k], lz);
      float d  = __fadd_rn(__fadd_rn(__fmul_rn(dx, dx), __fmul_rn(dy, dy)),
                           __fmul_rn(dz, dz));
      float m = fminf(mind[k], d);
      mind[k] = m;
      float sc = __fmul_rn(m, w[k]);
      bool g = sc > bs;
      bs = g ? sc : bs;
      bk = g ? k : bk;   // k is an inline constant -> no index array
    }
    // pack (score_bits, ~n): u64 max == (max score, then smallest index).
    // scores are >= 0 so float bit order == value order, and packed > 0
    // always, so the zero-initialized LDS slot is a safe identity.
    unsigned n = (unsigned)t + ((unsigned)bk << 10);   // n = t + bk*1024
    unsigned long long best =
        ((unsigned long long)__float_as_uint(bs) << 32) |
        (unsigned long long)(~n);

    // wave (64-lane) max reduce
#pragma unroll
    for (int off = 32; off > 0; off >>= 1) {
      unsigned long long o = __shfl_xor(best, off, 64);
      best = (o > best) ? o : best;
    }
    // cross-wave: wave leaders ds-atomicMax into this step's slot (race-free:
    // slot s touched only in step s), then one broadcast read after barrier.
    if ((t & 63) == 0) atomicMax(&wmax[s], best);
    __syncthreads();
    best = wmax[s];

    int cur = (int)(~(unsigned)best);
    cur = __builtin_amdgcn_readfirstlane(cur);  // wave-uniform -> scalar path

    if (t == 0) idx_out[(long long)b * FPS_S + s] = cur;

    // selected point coords: scalar (constant-cache) load, uniform address
    const float* q = xb + 3 * cur;
    lx = q[0]; ly = q[1]; lz = q[2];
  }
}

__global__ void gather_kernel(
    const float* __restrict__ xyz,    // [B,N,3]
    const float* __restrict__ feat,   // [B,C,N]
    const int*   __restrict__ label,  // [B,N]
    const int*   __restrict__ idx,    // [B,S]
    float*       __restrict__ out)
{
  const long long FEAT = (long long)FPS_B * FPS_C * FPS_S;  // 2097152
  const int XYZN = FPS_B * FPS_S * 3;                       // 49152
  const int LABN = FPS_B * FPS_S;                           // 16384
  long long i = (long long)blockIdx.x * blockDim.x + threadIdx.x;

  if (i < FEAT) {
    // sample_seg_feature [B,C,S]
    int s = (int)(i & (FPS_S - 1));
    int c = (int)((i >> 10) & (FPS_C - 1));
    int b = (int)(i >> 17);
    int n = idx[b * FPS_S + s];
    out[XYZN + i] = feat[((long long)(b * FPS_C + c)) * FPS_N + n];
  } else if (i < FEAT + XYZN) {
    // sampled_xyz [B,S,3]
    int j = (int)(i - FEAT);
    int d = j % 3;
    int sb = j / 3;
    int s = sb & (FPS_S - 1);
    int b = sb >> 10;
    int n = idx[b * FPS_S + s];
    out[j] = xyz[((long long)b * FPS_N + n) * 3 + d];
  } else if (i < FEAT + XYZN + LABN) {
    // sample_seg_label [B,S] as float
    int j = (int)(i - FEAT - XYZN);
    int s = j & (FPS_S - 1);
    int b = j >> 10;
    int n = idx[b * FPS_S + s];
    out[FEAT + XYZN + j] = (float)label[b * FPS_N + n];
  }
}

extern "C" void kernel_launch(void* const* d_in, const int* in_sizes, int n_in,
                              void* d_out, int out_size, void* d_ws, size_t ws_size,
                              hipStream_t stream) {
  const float* xyz   = (const float*)d_in[0];
  const float* feat  = (const float*)d_in[1];
  const int*   label = (const int*)d_in[2];
  float* out = (float*)d_out;
  int*   idx = (int*)d_ws;  // B*S ints = 64 KiB scratch

  wfps_kernel<<<FPS_B, FPS_T, 0, stream>>>(xyz, label, idx);

  const long long total = (long long)FPS_B * FPS_C * FPS_S
                        + (long long)FPS_B * FPS_S * 3
                        + (long long)FPS_B * FPS_S;  // 2162688
  gather_kernel<<<(int)((total + 255) / 256), 256, 0, stream>>>(
      xyz, feat, label, idx, out);
}

// Round 8
// 1854.056 us; speedup vs baseline: 2.3564x; 1.0207x over previous
//
#include <hip/hip_runtime.h>

// Weighted furthest point sampling + gathers for KeypointDetector.
// B=16, N=16384, C=128, S=1024, SEM=20.
//
// Multi-block FPS: 4 blocks per batch, per-step cross-block winner exchange
// via device-scope atomics on per-step slots (race-free, no counters).
//
// Output layout (float*, concatenated in reference return order):
//   [0, 49152)                  sampled_xyz      [B,S,3]
//   [49152, 49152+2097152)      sample_seg_feat  [B,C,S]
//   [2146304, 2162688)          sample_seg_label [B,S] (stored as float)

#define FPS_B   16
#define FPS_N   16384
#define FPS_C   128
#define FPS_S   1024
#define FPS_SEM 20
#define FPS_QB  4      // blocks per batch
#define FPS_MT  1024   // threads per block (multi)
#define FPS_MP  4      // points per thread (multi) = N / (QB*MT)

typedef unsigned long long ull;

// ---------------- zero the cross-block slot array (stale-ws hazard) --------
__global__ void zero_slots(ull* part) {
  int i = blockIdx.x * blockDim.x + threadIdx.x;  // 64*1024 == 65536 slots
  part[i] = 0ull;
}

// ---------------- multi-block weighted FPS ---------------------------------
__global__ __launch_bounds__(FPS_MT) void wfps_multi(
    const float* __restrict__ xyz,    // [B,N,3]
    const int*   __restrict__ label,  // [B,N]
    int*         __restrict__ idx_out, // [B,S]
    ull*         __restrict__ part)    // [B][QB][S] packed winners, pre-zeroed
{
  const int b = blockIdx.x & 15;   // blockIdx = q*16 + b -> batch's 4 blocks
  const int q = blockIdx.x >> 4;   // land on the same XCD under %8 round-robin
  const int t = threadIdx.x;

  __shared__ int counts[FPS_SEM];
  __shared__ ull wmax[FPS_S];      // per-step slot: local then global winner

  if (t < FPS_SEM) counts[t] = 0;
  wmax[t] = 0ull;                  // MT == S: each thread zeroes one slot
  __syncthreads();

  // ---- class-frequency weights: counts over the WHOLE batch (all 16384) ----
  const int* lab = label + b * FPS_N;
#pragma unroll
  for (int j = 0; j < 16; ++j)
    atomicAdd(&counts[lab[t + j * FPS_MT]], 1);
  __syncthreads();

  // ---- my 4 points: n = q*4096 + k*1024 + t ----
  const float* xb = xyz + b * FPS_N * 3;
  float px[FPS_MP], py[FPS_MP], pz[FPS_MP], w[FPS_MP], mind[FPS_MP];
#pragma unroll
  for (int k = 0; k < FPS_MP; ++k) {
    int n = q * 4096 + k * 1024 + t;
    px[k] = xb[n * 3 + 0];
    py[k] = xb[n * 3 + 1];
    pz[k] = xb[n * 3 + 2];
    w[k] = (float)counts[lab[n]];
    mind[k] = 1e10f;
    asm("" : "+v"(px[k]), "+v"(py[k]), "+v"(pz[k]), "+v"(w[k]));
  }

  if (q == 0 && t == 0) idx_out[b * FPS_S] = 0;
  float lx = xb[0], ly = xb[1], lz = xb[2];

  ull* pb = part + b * (FPS_QB * FPS_S);   // this batch's slots [q][s]

  for (int s = 1; s < FPS_S; ++s) {
    // local best over my 4 points (strict '>' keeps smallest k == smallest n)
    float bs = -1.0f;
    int bk = 0;
#pragma unroll
    for (int k = 0; k < FPS_MP; ++k) {
      // exact IEEE ops via _rn intrinsics: un-fusable, numpy summation order
      float dx = __fsub_rn(px[k], lx);
      float dy = __fsub_rn(py[k], ly);
      float dz = __fsub_rn(pz[k], lz);
      float d  = __fadd_rn(__fadd_rn(__fmul_rn(dx, dx), __fmul_rn(dy, dy)),
                           __fmul_rn(dz, dz));
      float m = fminf(mind[k], d);
      mind[k] = m;
      float sc = __fmul_rn(m, w[k]);
      bool g = sc > bs;
      bs = g ? sc : bs;
      bk = g ? k : bk;
    }
    // pack (score_bits, ~n): u64 max == (max score, then smallest index).
    // n <= 16383 -> ~n >= 0xFFFFC000 -> packed value is never 0.
    unsigned n = (unsigned)t + ((unsigned)bk << 10) + ((unsigned)q << 12);
    ull best = ((ull)__float_as_uint(bs) << 32) | (ull)(~n);

    // wave (64-lane) max reduce
#pragma unroll
    for (int off = 32; off > 0; off >>= 1) {
      ull o = __shfl_xor(best, off, 64);
      best = (o > best) ? o : best;
    }
    if ((t & 63) == 0) atomicMax(&wmax[s], best);   // LDS ds_max_u64
    __syncthreads();

    if (t == 0) {
      ull loc = wmax[s];
      // publish my quarter's winner, then poll the other three quarters.
      __hip_atomic_store(&pb[q * FPS_S + s], loc,
                         __ATOMIC_RELAXED, __HIP_MEMORY_SCOPE_AGENT);
      const int q1 = (q + 1) & 3, q2 = (q + 2) & 3, q3 = (q + 3) & 3;
      ull v1, v2, v3;
      do {   // three loads in flight per poll -> one round-trip per iteration
        v1 = __hip_atomic_load(&pb[q1 * FPS_S + s],
                               __ATOMIC_RELAXED, __HIP_MEMORY_SCOPE_AGENT);
        v2 = __hip_atomic_load(&pb[q2 * FPS_S + s],
                               __ATOMIC_RELAXED, __HIP_MEMORY_SCOPE_AGENT);
        v3 = __hip_atomic_load(&pb[q3 * FPS_S + s],
                               __ATOMIC_RELAXED, __HIP_MEMORY_SCOPE_AGENT);
      } while (!(v1 && v2 && v3));
      ull m = loc;
      m = (v1 > m) ? v1 : m;
      m = (v2 > m) ? v2 : m;
      m = (v3 > m) ? v3 : m;
      wmax[s] = m;   // overwrite slot with the global winner
    }
    __syncthreads();

    ull g = wmax[s];
    int cur = (int)(~(unsigned)g);
    cur = __builtin_amdgcn_readfirstlane(cur);

    if (q == 0 && t == 0) idx_out[b * FPS_S + s] = cur;

    const float* qq = xb + 3 * cur;   // uniform cached load
    lx = qq[0]; ly = qq[1]; lz = qq[2];
  }
}

// ---------------- single-block fallback (R7, proven, used if ws too small) --
__global__ __launch_bounds__(1024)
__attribute__((amdgpu_waves_per_eu(4, 4)))
void wfps_single(
    const float* __restrict__ xyz,
    const int*   __restrict__ label,
    int*         __restrict__ idx_out)
{
  const int b = blockIdx.x;
  const int t = threadIdx.x;

  __shared__ int counts[FPS_SEM];
  __shared__ ull wmax[FPS_S];

  if (t < FPS_SEM) counts[t] = 0;
  wmax[t] = 0ull;
  __syncthreads();

  const int* lab = label + b * FPS_N;
  int mylab[16];
#pragma unroll
  for (int k = 0; k < 16; ++k) {
    mylab[k] = lab[t + k * 1024];
    atomicAdd(&counts[mylab[k]], 1);
  }
  __syncthreads();

  const float* xb = xyz + b * FPS_N * 3;
  float px[16], py[16], pz[16], w[16], mind[16];
#pragma unroll
  for (int k = 0; k < 16; ++k) {
    int n = t + k * 1024;
    px[k] = xb[n * 3 + 0];
    py[k] = xb[n * 3 + 1];
    pz[k] = xb[n * 3 + 2];
    w[k] = (float)counts[mylab[k]];
    mind[k] = 1e10f;
    asm("" : "+v"(px[k]), "+v"(py[k]), "+v"(pz[k]), "+v"(w[k]));
  }

  if (t == 0) idx_out[b * FPS_S] = 0;
  float lx = xb[0], ly = xb[1], lz = xb[2];

  for (int s = 1; s < FPS_S; ++s) {
    float bs = -1.0f;
    int bk = 0;
#pragma unroll
    for (int k = 0; k < 16; ++k) {
      float dx = __fsub_rn(px[k], lx);
      float dy = __fsub_rn(py[k], ly);
      float dz = __fsub_rn(pz[k], lz);
      float d  = __fadd_rn(__fadd_rn(__fmul_rn(dx, dx), __fmul_rn(dy, dy)),
                           __fmul_rn(dz, dz));
      float m = fminf(mind[k], d);
      mind[k] = m;
      float sc = __fmul_rn(m, w[k]);
      bool g = sc > bs;
      bs = g ? sc : bs;
      bk = g ? k : bk;
    }
    unsigned n = (unsigned)t + ((unsigned)bk << 10);
    ull best = ((ull)__float_as_uint(bs) << 32) | (ull)(~n);
#pragma unroll
    for (int off = 32; off > 0; off >>= 1) {
      ull o = __shfl_xor(best, off, 64);
      best = (o > best) ? o : best;
    }
    if ((t & 63) == 0) atomicMax(&wmax[s], best);
    __syncthreads();
    best = wmax[s];

    int cur = (int)(~(unsigned)best);
    cur = __builtin_amdgcn_readfirstlane(cur);
    if (t == 0) idx_out[b * FPS_S + s] = cur;
    const float* qq = xb + 3 * cur;
    lx = qq[0]; ly = qq[1]; lz = qq[2];
  }
}

// ---------------- gathers ---------------------------------------------------
__global__ void gather_kernel(
    const float* __restrict__ xyz,    // [B,N,3]
    const float* __restrict__ feat,   // [B,C,N]
    const int*   __restrict__ label,  // [B,N]
    const int*   __restrict__ idx,    // [B,S]
    float*       __restrict__ out)
{
  const long long FEAT = (long long)FPS_B * FPS_C * FPS_S;  // 2097152
  const int XYZN = FPS_B * FPS_S * 3;                       // 49152
  const int LABN = FPS_B * FPS_S;                           // 16384
  long long i = (long long)blockIdx.x * blockDim.x + threadIdx.x;

  if (i < FEAT) {
    int s = (int)(i & (FPS_S - 1));
    int c = (int)((i >> 10) & (FPS_C - 1));
    int b = (int)(i >> 17);
    int n = idx[b * FPS_S + s];
    out[XYZN + i] = feat[((long long)(b * FPS_C + c)) * FPS_N + n];
  } else if (i < FEAT + XYZN) {
    int j = (int)(i - FEAT);
    int d = j % 3;
    int sb = j / 3;
    int s = sb & (FPS_S - 1);
    int b = sb >> 10;
    int n = idx[b * FPS_S + s];
    out[j] = xyz[((long long)b * FPS_N + n) * 3 + d];
  } else if (i < FEAT + XYZN + LABN) {
    int j = (int)(i - FEAT - XYZN);
    int s = j & (FPS_S - 1);
    int b = j >> 10;
    int n = idx[b * FPS_S + s];
    out[FEAT + XYZN + j] = (float)label[b * FPS_N + n];
  }
}

extern "C" void kernel_launch(void* const* d_in, const int* in_sizes, int n_in,
                              void* d_out, int out_size, void* d_ws, size_t ws_size,
                              hipStream_t stream) {
  const float* xyz   = (const float*)d_in[0];
  const float* feat  = (const float*)d_in[1];
  const int*   label = (const int*)d_in[2];
  float* out = (float*)d_out;
  int*   idx = (int*)d_ws;                         // [0, 64KB): idx int[16][1024]
  ull*   part = (ull*)((char*)d_ws + 65536);       // [64KB, 576KB): slots

  const size_t need = 65536 + (size_t)FPS_B * FPS_QB * FPS_S * 8;  // 589824

  if (ws_size >= need) {
    zero_slots<<<64, 1024, 0, stream>>>(part);
    wfps_multi<<<FPS_B * FPS_QB, FPS_MT, 0, stream>>>(xyz, label, idx, part);
  } else {
    wfps_single<<<FPS_B, 1024, 0, stream>>>(xyz, label, idx);
  }

  const long long total = (long long)FPS_B * FPS_C * FPS_S
                        + (long long)FPS_B * FPS_S * 3
                        + (long long)FPS_B * FPS_S;  // 2162688
  gather_kernel<<<(int)((total + 255) / 256), 256, 0, stream>>>(
      xyz, feat, label, idx, out);
}

// Round 9
// 1853.163 us; speedup vs baseline: 2.3575x; 1.0005x over previous
//
#include <hip/hip_runtime.h>

// Weighted furthest point sampling + gathers for KeypointDetector.
// B=16, N=16384, C=128, S=1024, SEM=20.
//
// Multi-block FPS: 4 blocks per batch, per-step cross-block winner exchange
// via device-scope atomics on per-step slots (race-free, no counters).
//
// Output layout (float*, concatenated in reference return order):
//   [0, 49152)                  sampled_xyz      [B,S,3]
//   [49152, 49152+2097152)      sample_seg_feat  [B,C,S]
//   [2146304, 2162688)          sample_seg_label [B,S] (stored as float)

#define FPS_B   16
#define FPS_N   16384
#define FPS_C   128
#define FPS_S   1024
#define FPS_SEM 20
#define FPS_QB  4      // blocks per batch
#define FPS_MT  1024   // threads per block (multi)
#define FPS_MP  4      // points per thread (multi) = N / (QB*MT)

typedef unsigned long long ull;

// ---------------- zero the cross-block slot array (stale-ws hazard) --------
__global__ void zero_slots(ull* part) {
  int i = blockIdx.x * blockDim.x + threadIdx.x;  // 64*1024 == 65536 slots
  part[i] = 0ull;
}

// ---------------- multi-block weighted FPS ---------------------------------
__global__ __launch_bounds__(FPS_MT) void wfps_multi(
    const float* __restrict__ xyz,    // [B,N,3]
    const int*   __restrict__ label,  // [B,N]
    int*         __restrict__ idx_out, // [B,S]
    ull*         __restrict__ part)    // [B][QB][S] packed winners, pre-zeroed
{
  const int b = blockIdx.x & 15;   // blockIdx = q*16 + b -> batch's 4 blocks
  const int q = blockIdx.x >> 4;   // land on the same XCD under %8 round-robin
  const int t = threadIdx.x;

  __shared__ int counts[FPS_SEM];
  __shared__ ull wmax[FPS_S];      // per-step slot: local then global winner

  if (t < FPS_SEM) counts[t] = 0;
  wmax[t] = 0ull;                  // MT == S: each thread zeroes one slot
  __syncthreads();

  // ---- class-frequency weights: counts over the WHOLE batch (all 16384) ----
  const int* lab = label + b * FPS_N;
#pragma unroll
  for (int j = 0; j < 16; ++j)
    atomicAdd(&counts[lab[t + j * FPS_MT]], 1);
  __syncthreads();

  // ---- my 4 points: n = q*4096 + k*1024 + t ----
  const float* xb = xyz + b * FPS_N * 3;
  float px[FPS_MP], py[FPS_MP], pz[FPS_MP], w[FPS_MP], mind[FPS_MP];
#pragma unroll
  for (int k = 0; k < FPS_MP; ++k) {
    int n = q * 4096 + k * 1024 + t;
    px[k] = xb[n * 3 + 0];
    py[k] = xb[n * 3 + 1];
    pz[k] = xb[n * 3 + 2];
    w[k] = (float)counts[lab[n]];
    mind[k] = 1e10f;
    asm("" : "+v"(px[k]), "+v"(py[k]), "+v"(pz[k]), "+v"(w[k]));
  }

  if (q == 0 && t == 0) idx_out[b * FPS_S] = 0;
  float lx = xb[0], ly = xb[1], lz = xb[2];

  ull* pb = part + b * (FPS_QB * FPS_S);   // this batch's slots [q][s]

  for (int s = 1; s < FPS_S; ++s) {
    // local best over my 4 points (strict '>' keeps smallest k == smallest n)
    float bs = -1.0f;
    int bk = 0;
#pragma unroll
    for (int k = 0; k < FPS_MP; ++k) {
      // exact IEEE ops via _rn intrinsics: un-fusable, numpy summation order
      float dx = __fsub_rn(px[k], lx);
      float dy = __fsub_rn(py[k], ly);
      float dz = __fsub_rn(pz[k], lz);
      float d  = __fadd_rn(__fadd_rn(__fmul_rn(dx, dx), __fmul_rn(dy, dy)),
                           __fmul_rn(dz, dz));
      float m = fminf(mind[k], d);
      mind[k] = m;
      float sc = __fmul_rn(m, w[k]);
      bool g = sc > bs;
      bs = g ? sc : bs;
      bk = g ? k : bk;
    }
    // pack (score_bits, ~n): u64 max == (max score, then smallest index).
    // n <= 16383 -> ~n >= 0xFFFFC000 -> packed value is never 0.
    unsigned n = (unsigned)t + ((unsigned)bk << 10) + ((unsigned)q << 12);
    ull best = ((ull)__float_as_uint(bs) << 32) | (ull)(~n);

    // wave (64-lane) max reduce
#pragma unroll
    for (int off = 32; off > 0; off >>= 1) {
      ull o = __shfl_xor(best, off, 64);
      best = (o > best) ? o : best;
    }
    if ((t & 63) == 0) atomicMax(&wmax[s], best);   // LDS ds_max_u64
    __syncthreads();

    if (t == 0) {
      ull loc = wmax[s];
      // publish my quarter's winner, then poll the other three quarters.
      __hip_atomic_store(&pb[q * FPS_S + s], loc,
                         __ATOMIC_RELAXED, __HIP_MEMORY_SCOPE_AGENT);
      const int q1 = (q + 1) & 3, q2 = (q + 2) & 3, q3 = (q + 3) & 3;
      ull v1, v2, v3;
      do {   // three loads in flight per poll -> one round-trip per iteration
        v1 = __hip_atomic_load(&pb[q1 * FPS_S + s],
                               __ATOMIC_RELAXED, __HIP_MEMORY_SCOPE_AGENT);
        v2 = __hip_atomic_load(&pb[q2 * FPS_S + s],
                               __ATOMIC_RELAXED, __HIP_MEMORY_SCOPE_AGENT);
        v3 = __hip_atomic_load(&pb[q3 * FPS_S + s],
                               __ATOMIC_RELAXED, __HIP_MEMORY_SCOPE_AGENT);
      } while (!(v1 && v2 && v3));
      ull m = loc;
      m = (v1 > m) ? v1 : m;
      m = (v2 > m) ? v2 : m;
      m = (v3 > m) ? v3 : m;
      wmax[s] = m;   // overwrite slot with the global winner
    }
    __syncthreads();

    ull g = wmax[s];
    int cur = (int)(~(unsigned)g);
    cur = __builtin_amdgcn_readfirstlane(cur);

    if (q == 0 && t == 0) idx_out[b * FPS_S + s] = cur;

    const float* qq = xb + 3 * cur;   // uniform cached load
    lx = qq[0]; ly = qq[1]; lz = qq[2];
  }
}

// ---------------- single-block fallback (R7, proven, used if ws too small) --
__global__ __launch_bounds__(1024)
__attribute__((amdgpu_waves_per_eu(4, 4)))
void wfps_single(
    const float* __restrict__ xyz,
    const int*   __restrict__ label,
    int*         __restrict__ idx_out)
{
  const int b = blockIdx.x;
  const int t = threadIdx.x;

  __shared__ int counts[FPS_SEM];
  __shared__ ull wmax[FPS_S];

  if (t < FPS_SEM) counts[t] = 0;
  wmax[t] = 0ull;
  __syncthreads();

  const int* lab = label + b * FPS_N;
  int mylab[16];
#pragma unroll
  for (int k = 0; k < 16; ++k) {
    mylab[k] = lab[t + k * 1024];
    atomicAdd(&counts[mylab[k]], 1);
  }
  __syncthreads();

  const float* xb = xyz + b * FPS_N * 3;
  float px[16], py[16], pz[16], w[16], mind[16];
#pragma unroll
  for (int k = 0; k < 16; ++k) {
    int n = t + k * 1024;
    px[k] = xb[n * 3 + 0];
    py[k] = xb[n * 3 + 1];
    pz[k] = xb[n * 3 + 2];
    w[k] = (float)counts[mylab[k]];
    mind[k] = 1e10f;
    asm("" : "+v"(px[k]), "+v"(py[k]), "+v"(pz[k]), "+v"(w[k]));
  }

  if (t == 0) idx_out[b * FPS_S] = 0;
  float lx = xb[0], ly = xb[1], lz = xb[2];

  for (int s = 1; s < FPS_S; ++s) {
    float bs = -1.0f;
    int bk = 0;
#pragma unroll
    for (int k = 0; k < 16; ++k) {
      float dx = __fsub_rn(px[k], lx);
      float dy = __fsub_rn(py[k], ly);
      float dz = __fsub_rn(pz[k], lz);
      float d  = __fadd_rn(__fadd_rn(__fmul_rn(dx, dx), __fmul_rn(dy, dy)),
                           __fmul_rn(dz, dz));
      float m = fminf(mind[k], d);
      mind[k] = m;
      float sc = __fmul_rn(m, w[k]);
      bool g = sc > bs;
      bs = g ? sc : bs;
      bk = g ? k : bk;
    }
    unsigned n = (unsigned)t + ((unsigned)bk << 10);
    ull best = ((ull)__float_as_uint(bs) << 32) | (ull)(~n);
#pragma unroll
    for (int off = 32; off > 0; off >>= 1) {
      ull o = __shfl_xor(best, off, 64);
      best = (o > best) ? o : best;
    }
    if ((t & 63) == 0) atomicMax(&wmax[s], best);
    __syncthreads();
    best = wmax[s];

    int cur = (int)(~(unsigned)best);
    cur = __builtin_amdgcn_readfirstlane(cur);
    if (t == 0) idx_out[b * FPS_S + s] = cur;
    const float* qq = xb + 3 * cur;
    lx = qq[0]; ly = qq[1]; lz = qq[2];
  }
}

// ---------------- gathers ---------------------------------------------------
__global__ void gather_kernel(
    const float* __restrict__ xyz,    // [B,N,3]
    const float* __restrict__ feat,   // [B,C,N]
    const int*   __restrict__ label,  // [B,N]
    const int*   __restrict__ idx,    // [B,S]
    float*       __restrict__ out)
{
  const long long FEAT = (long long)FPS_B * FPS_C * FPS_S;  // 2097152
  const int XYZN = FPS_B * FPS_S * 3;                       // 49152
  const int LABN = FPS_B * FPS_S;                           // 16384
  long long i = (long long)blockIdx.x * blockDim.x + threadIdx.x;

  if (i < FEAT) {
    int s = (int)(i & (FPS_S - 1));
    int c = (int)((i >> 10) & (FPS_C - 1));
    int b = (int)(i >> 17);
    int n = idx[b * FPS_S + s];
    out[XYZN + i] = feat[((long long)(b * FPS_C + c)) * FPS_N + n];
  } else if (i < FEAT + XYZN) {
    int j = (int)(i - FEAT);
    int d = j % 3;
    int sb = j / 3;
    int s = sb & (FPS_S - 1);
    int b = sb >> 10;
    int n = idx[b * FPS_S + s];
    out[j] = xyz[((long long)b * FPS_N + n) * 3 + d];
  } else if (i < FEAT + XYZN + LABN) {
    int j = (int)(i - FEAT - XYZN);
    int s = j & (FPS_S - 1);
    int b = j >> 10;
    int n = idx[b * FPS_S + s];
    out[FEAT + XYZN + j] = (float)label[b * FPS_N + n];
  }
}

extern "C" void kernel_launch(void* const* d_in, const int* in_sizes, int n_in,
                              void* d_out, int out_size, void* d_ws, size_t ws_size,
                              hipStream_t stream) {
  const float* xyz   = (const float*)d_in[0];
  const float* feat  = (const float*)d_in[1];
  const int*   label = (const int*)d_in[2];
  float* out = (float*)d_out;
  int*   idx = (int*)d_ws;                         // [0, 64KB): idx int[16][1024]
  ull*   part = (ull*)((char*)d_ws + 65536);       // [64KB, 576KB): slots

  const size_t need = 65536 + (size_t)FPS_B * FPS_QB * FPS_S * 8;  // 589824

  if (ws_size >= need) {
    zero_slots<<<64, 1024, 0, stream>>>(part);
    wfps_multi<<<FPS_B * FPS_QB, FPS_MT, 0, stream>>>(xyz, label, idx, part);
  } else {
    wfps_single<<<FPS_B, 1024, 0, stream>>>(xyz, label, idx);
  }

  const long long total = (long long)FPS_B * FPS_C * FPS_S
                        + (long long)FPS_B * FPS_S * 3
                        + (long long)FPS_B * FPS_S;  // 2162688
  gather_kernel<<<(int)((total + 255) / 256), 256, 0, stream>>>(
      xyz, feat, label, idx, out);
}